// Round 1
// baseline (6008.702 us; speedup 1.0000x reference)
//
#include <hip/hip_runtime.h>
#include <math.h>

// ---------------------------------------------------------------------------
// BitResidualBlock: 3 stages of (dilated bitconv -> snake -> bitconv -> +res)
// B=8, C=512, T=4096, K=3, dilations {1,3,5}. fp32 baseline, VALU-bound.
// ws layout (floats): partials[6*96] | s[6] | wq1[3*C*C*K] (layout [i][ci][k][co])
//                     | wq2[...] | exp(alpha)[3*C] | 1/(exp(beta)+eps)[3*C]
//                     | h[B*C*T]
// Total ws need: ~86 MB.
// ---------------------------------------------------------------------------

constexpr int B_ = 8, C_ = 512, T_ = 4096, K_ = 3;
constexpr int WELEM = C_ * C_ * K_;          // 786432 per tensor

constexpr size_t OFF_PART = 0;               // 6*96 partial sums
constexpr size_t OFF_S    = 640;             // 6 scales
constexpr size_t OFF_WQ1  = 1024;
constexpr size_t OFF_WQ2  = OFF_WQ1 + 3 * (size_t)WELEM;
constexpr size_t OFF_AE   = OFF_WQ2 + 3 * (size_t)WELEM;
constexpr size_t OFF_IB   = OFF_AE + 3 * C_;
constexpr size_t OFF_H    = OFF_IB + 3 * C_; // 4722688 -> h = B*C*T floats

// --------------------------- absmean (deterministic) -----------------------
__global__ __launch_bounds__(256)
void absmean_partial(const float* __restrict__ w1, const float* __restrict__ w2,
                     float* __restrict__ part) {
  __shared__ float red[256];
  const int t = blockIdx.y;  // tensor 0..5
  const float* src = (t < 3) ? (w1 + (size_t)t * WELEM)
                             : (w2 + (size_t)(t - 3) * WELEM);
  const int base = blockIdx.x * (256 * 32);
  float v = 0.f;
#pragma unroll
  for (int j = 0; j < 32; ++j) v += fabsf(src[base + j * 256 + threadIdx.x]);
  red[threadIdx.x] = v;
  __syncthreads();
  for (int s = 128; s > 0; s >>= 1) {
    if (threadIdx.x < (unsigned)s) red[threadIdx.x] += red[threadIdx.x + s];
    __syncthreads();
  }
  if (threadIdx.x == 0) part[t * 96 + blockIdx.x] = red[0];
}

__global__ __launch_bounds__(128)
void absmean_final(const float* __restrict__ part, float* __restrict__ svec) {
  __shared__ float red[128];
  const int t = blockIdx.x;
  red[threadIdx.x] = (threadIdx.x < 96) ? part[t * 96 + threadIdx.x] : 0.f;
  __syncthreads();
  for (int s = 64; s > 0; s >>= 1) {
    if (threadIdx.x < (unsigned)s) red[threadIdx.x] += red[threadIdx.x + s];
    __syncthreads();
  }
  if (threadIdx.x == 0) svec[t] = red[0] / (float)WELEM;
}

// --------------------------- quantize + transpose --------------------------
// dst layout: [i][ci][k][co]  (co contiguous -> coalesced LDS staging later)
__global__ __launch_bounds__(256)
void quantize_kernel(const float* __restrict__ src, float* __restrict__ dst,
                     const float* __restrict__ svec, int sbase) {
  const int idx = blockIdx.x * 256 + threadIdx.x;  // over 3*WELEM (exact grid)
  const int co = idx & (C_ - 1);
  const int k  = (idx / C_) % K_;
  const int ci = (idx / (C_ * K_)) & (C_ - 1);
  const int i  = idx / (C_ * K_ * C_);
  const float s = svec[sbase + i];
  const float w = src[(((size_t)i * C_ + co) * C_ + ci) * K_ + k];
  float q = rintf(w / (s + 1e-5f));             // round-half-even, like jnp.round
  q = fminf(1.f, fmaxf(-1.f, q));
  dst[idx] = q * s;
}

__global__ __launch_bounds__(256)
void snake_params_kernel(const float* __restrict__ al, const float* __restrict__ be,
                         float* __restrict__ ae, float* __restrict__ ib) {
  const int idx = blockIdx.x * 256 + threadIdx.x;
  if (idx < 3 * C_) {
    ae[idx] = expf(al[idx]);
    ib[idx] = 1.f / (expf(be[idx]) + 1e-9f);
  }
}

// ------------------------------- conv kernel --------------------------------
// y[b,co,t] = sum_{ci,k} W[ci,k,co] * x[b,ci,t+(k-1)*DIL]  (+bias, then
// SNAKE ? snake() : +res).  Tile: 128 co x 128 t, 256 thr, 8x8 microtile.
template <int DIL, bool SNAKE>
__global__ __launch_bounds__(256, 3)
void conv_kernel(const float* __restrict__ X, const float* __restrict__ W,
                 const float* __restrict__ bias, const float* __restrict__ aexp,
                 const float* __restrict__ invb, const float* __restrict__ res,
                 float* __restrict__ Y) {
  constexpr int TT = 128, COT = 128, CIC = 16;
  constexpr int XN = TT + 2 * DIL;            // valid cols in X tile
  constexpr int XW = (XN + 3) & ~3;           // padded row stride (16B align)
  __shared__ float Xs[CIC * XW];
  __shared__ float Ws[CIC * K_ * COT];        // layout [ci][k][co]

  const int b   = blockIdx.z;
  const int co0 = blockIdx.y * COT;
  const int t0  = blockIdx.x * TT;
  const int tid = threadIdx.x;
  const int tt  = tid & 15;                   // t-tile lane   (8 cols each)
  const int tco = tid >> 4;                   // co-tile lane  (8 rows each)

  float acc[8][8];
#pragma unroll
  for (int i = 0; i < 8; ++i)
#pragma unroll
    for (int j = 0; j < 8; ++j) acc[i][j] = 0.f;

  const float* Xb = X + (size_t)b * C_ * T_;

  for (int cc = 0; cc < C_ / CIC; ++cc) {
    // ---- stage X tile (with halo, zero-padded at sequence edges) ----
#pragma unroll
    for (int l = 0; l < (CIC * XN + 255) / 256; ++l) {
      const int idx = l * 256 + tid;
      if (idx < CIC * XN) {
        const int row = idx / XN;
        const int col = idx - row * XN;
        const int t = t0 - DIL + col;
        float v = 0.f;
        if ((unsigned)t < (unsigned)T_) v = Xb[(cc * CIC + row) * T_ + t];
        Xs[row * XW + col] = v;
      }
    }
    // ---- stage W tile: 16*3*128 floats, coalesced ----
    const float* Wg = W + (size_t)cc * CIC * K_ * C_ + co0;
#pragma unroll
    for (int l = 0; l < 24; ++l) {
      const int idx = l * 256 + tid;
      const int rk = idx >> 7;                // (ci*3+k)
      const int co = idx & 127;
      Ws[idx] = Wg[rk * C_ + co];
    }
    __syncthreads();

#pragma unroll 1
    for (int ci = 0; ci < CIC; ++ci) {
      float xw[8 + 2 * DIL];
#pragma unroll
      for (int j = 0; j < 8 + 2 * DIL; ++j) xw[j] = Xs[ci * XW + tt * 8 + j];
      float wv[K_][8];
#pragma unroll
      for (int k = 0; k < K_; ++k)
#pragma unroll
        for (int i = 0; i < 8; ++i) wv[k][i] = Ws[(ci * K_ + k) * COT + tco * 8 + i];
#pragma unroll
      for (int k = 0; k < K_; ++k)
#pragma unroll
        for (int i = 0; i < 8; ++i)
#pragma unroll
          for (int j = 0; j < 8; ++j)
            acc[i][j] = fmaf(wv[k][i], xw[j + k * DIL], acc[i][j]);
    }
    __syncthreads();
  }

  // ---- epilogue: bias + (snake | residual), vectorized store ----
#pragma unroll
  for (int i = 0; i < 8; ++i) {
    const int co = co0 + tco * 8 + i;
    const float bs = bias[co];
    const size_t base = ((size_t)b * C_ + co) * T_ + t0 + tt * 8;
    float o[8];
    if (SNAKE) {
      const float a  = aexp[co];
      const float ib = invb[co];
#pragma unroll
      for (int j = 0; j < 8; ++j) {
        const float v = acc[i][j] + bs;
        const float s = sinf(a * v);
        o[j] = v + ib * s * s;
      }
    } else {
      const float4 r0 = *(const float4*)(res + base);
      const float4 r1 = *(const float4*)(res + base + 4);
      const float r[8] = {r0.x, r0.y, r0.z, r0.w, r1.x, r1.y, r1.z, r1.w};
#pragma unroll
      for (int j = 0; j < 8; ++j) o[j] = acc[i][j] + bs + r[j];
    }
    *(float4*)(Y + base)     = make_float4(o[0], o[1], o[2], o[3]);
    *(float4*)(Y + base + 4) = make_float4(o[4], o[5], o[6], o[7]);
  }
}

// ------------------------------- launch -------------------------------------
extern "C" void kernel_launch(void* const* d_in, const int* in_sizes, int n_in,
                              void* d_out, int out_size, void* d_ws, size_t ws_size,
                              hipStream_t stream) {
  (void)in_sizes; (void)n_in; (void)out_size; (void)ws_size;
  const float* x  = (const float*)d_in[0];
  const float* w1 = (const float*)d_in[1];
  const float* b1 = (const float*)d_in[2];
  const float* al = (const float*)d_in[3];
  const float* be = (const float*)d_in[4];
  const float* w2 = (const float*)d_in[5];
  const float* b2 = (const float*)d_in[6];
  float* out = (float*)d_out;
  float* ws  = (float*)d_ws;

  float* part = ws + OFF_PART;
  float* svec = ws + OFF_S;
  float* wq1  = ws + OFF_WQ1;
  float* wq2  = ws + OFF_WQ2;
  float* ae   = ws + OFF_AE;
  float* ib   = ws + OFF_IB;
  float* h    = ws + OFF_H;

  absmean_partial<<<dim3(96, 6), 256, 0, stream>>>(w1, w2, part);
  absmean_final<<<6, 128, 0, stream>>>(part, svec);
  quantize_kernel<<<(3 * WELEM) / 256, 256, 0, stream>>>(w1, wq1, svec, 0);
  quantize_kernel<<<(3 * WELEM) / 256, 256, 0, stream>>>(w2, wq2, svec, 3);
  snake_params_kernel<<<6, 256, 0, stream>>>(al, be, ae, ib);

  const dim3 grid(T_ / 128, C_ / 128, B_);

  // stage 0 (dil=1)
  conv_kernel<1, true ><<<grid, 256, 0, stream>>>(x,   wq1 + 0 * (size_t)WELEM, b1 + 0,      ae + 0,      ib + 0,      nullptr, h);
  conv_kernel<1, false><<<grid, 256, 0, stream>>>(h,   wq2 + 0 * (size_t)WELEM, b2 + 0,      nullptr,     nullptr,     x,       out);
  // stage 1 (dil=3)
  conv_kernel<3, true ><<<grid, 256, 0, stream>>>(out, wq1 + 1 * (size_t)WELEM, b1 + C_,     ae + C_,     ib + C_,     nullptr, h);
  conv_kernel<1, false><<<grid, 256, 0, stream>>>(h,   wq2 + 1 * (size_t)WELEM, b2 + C_,     nullptr,     nullptr,     out,     out);
  // stage 2 (dil=5)
  conv_kernel<5, true ><<<grid, 256, 0, stream>>>(out, wq1 + 2 * (size_t)WELEM, b1 + 2 * C_, ae + 2 * C_, ib + 2 * C_, nullptr, h);
  conv_kernel<1, false><<<grid, 256, 0, stream>>>(h,   wq2 + 2 * (size_t)WELEM, b2 + 2 * C_, nullptr,     nullptr,     out,     out);
}

// Round 2
// 870.411 us; speedup vs baseline: 6.9033x; 6.9033x over previous
//
#include <hip/hip_runtime.h>
#include <math.h>
#include <stdint.h>

// ---------------------------------------------------------------------------
// BitResidualBlock via bf16-split MFMA.
// Ternary weights (exact in bf16) x activations split hi/lo bf16:
//   x = hi + lo  (each product with q in {-1,0,1} is exact; fp32 accum)
// Conv as GEMM: D[co,t] = sum_ci,tap Wq_tap[co,ci] * X[ci, t+(tap-1)*d],
// mfma_f32_16x16x32_bf16, A=W (pre-swizzled, direct global->reg, L2-resident),
// B=X^T [b][t][c] hi/lo staged in LDS (rows padded to 80 B -> 2-way, free).
// ---------------------------------------------------------------------------

constexpr int B_ = 8, C_ = 512, T_ = 4096, K_ = 3;
constexpr int WELEM = C_ * C_ * K_;  // 786432 per tensor

typedef __bf16 bf16x8 __attribute__((ext_vector_type(8)));
typedef float f32x4 __attribute__((ext_vector_type(4)));
typedef unsigned short u16x8 __attribute__((ext_vector_type(8)));

// ws byte offsets
constexpr size_t OFF_PART = 0;
constexpr size_t OFF_S = 4096;
constexpr size_t OFF_AE = 8192;
constexpr size_t OFF_IB = 16384;
constexpr size_t OFF_WQ1 = 32768;                          // ushort[3*WELEM]
constexpr size_t OFF_WQ2 = OFF_WQ1 + (size_t)3 * WELEM * 2;
constexpr size_t OFF_H = OFF_WQ2 + (size_t)3 * WELEM * 2;  // float[B*C*T]
constexpr size_t NBCT = (size_t)B_ * C_ * T_;
constexpr size_t OFF_AHI = OFF_H + NBCT * 4;
constexpr size_t OFF_ALO = OFF_AHI + NBCT * 2;
constexpr size_t OFF_BHI = OFF_ALO + NBCT * 2;
constexpr size_t OFF_BLO = OFF_BHI + NBCT * 2;

__device__ inline unsigned short bf16_rne(float v) {
  unsigned int u = __builtin_bit_cast(unsigned int, v);
  unsigned int r = u + 0x7FFFu + ((u >> 16) & 1u);
  return (unsigned short)(r >> 16);
}

// --------------------------- absmean (deterministic, same as R1) ------------
__global__ __launch_bounds__(256)
void absmean_partial(const float* __restrict__ w1, const float* __restrict__ w2,
                     float* __restrict__ part) {
  __shared__ float red[256];
  const int t = blockIdx.y;
  const float* src = (t < 3) ? (w1 + (size_t)t * WELEM) : (w2 + (size_t)(t - 3) * WELEM);
  const int base = blockIdx.x * (256 * 32);
  float v = 0.f;
#pragma unroll
  for (int j = 0; j < 32; ++j) v += fabsf(src[base + j * 256 + threadIdx.x]);
  red[threadIdx.x] = v;
  __syncthreads();
  for (int s = 128; s > 0; s >>= 1) {
    if (threadIdx.x < (unsigned)s) red[threadIdx.x] += red[threadIdx.x + s];
    __syncthreads();
  }
  if (threadIdx.x == 0) part[t * 96 + blockIdx.x] = red[0];
}

__global__ __launch_bounds__(128)
void absmean_final(const float* __restrict__ part, float* __restrict__ svec) {
  __shared__ float red[128];
  const int t = blockIdx.x;
  red[threadIdx.x] = (threadIdx.x < 96) ? part[t * 96 + threadIdx.x] : 0.f;
  __syncthreads();
  for (int s = 64; s > 0; s >>= 1) {
    if (threadIdx.x < (unsigned)s) red[threadIdx.x] += red[threadIdx.x + s];
    __syncthreads();
  }
  if (threadIdx.x == 0) svec[t] = red[0] / (float)WELEM;
}

// --------------------------- quantize -> ternary bf16, frag-swizzled --------
// dst layout: idx = (((st*16 + cc)*3 + tap)*32 + cot)*512 + lane*8 + j
//   where co = cot*16 + (lane&15), ci = cc*32 + (lane>>4)*8 + j.
// A-frag for (cc,tap,co-tile) is then a contiguous 1 KiB block, 16 B/lane.
__global__ __launch_bounds__(256)
void quantize_kernel(const float* __restrict__ src, unsigned short* __restrict__ dst,
                     const float* __restrict__ svec, int sbase) {
  const int idx = blockIdx.x * 256 + threadIdx.x;  // exact grid over 3*WELEM
  const int j = idx & 7;
  const int lane = (idx >> 3) & 63;
  const int cot = (idx >> 9) & 31;
  const int rest = idx >> 14;
  const int tap = rest % 3;
  const int rest2 = rest / 3;
  const int cc = rest2 & 15;
  const int st = rest2 >> 4;
  const int co = cot * 16 + (lane & 15);
  const int ci = cc * 32 + (lane >> 4) * 8 + j;
  const float s = svec[sbase + st];
  const float w = src[(((size_t)st * C_ + co) * C_ + ci) * K_ + tap];
  float q = rintf(w / (s + 1e-5f));
  q = fminf(1.f, fmaxf(-1.f, q));
  dst[idx] = (unsigned short)(__builtin_bit_cast(unsigned int, q) >> 16);
}

__global__ __launch_bounds__(256)
void snake_params_kernel(const float* __restrict__ al, const float* __restrict__ be,
                         float* __restrict__ ae, float* __restrict__ ib) {
  const int idx = blockIdx.x * 256 + threadIdx.x;
  if (idx < 3 * C_) {
    ae[idx] = expf(al[idx]);
    ib[idx] = 1.f / (expf(be[idx]) + 1e-9f);
  }
}

// --------------------------- transpose + hi/lo split ------------------------
// in:  fp32 [b][C][T];  out: bf16-bits hi/lo [b][T][C]
__global__ __launch_bounds__(256)
void transpose_split(const float* __restrict__ X, unsigned short* __restrict__ Hi,
                     unsigned short* __restrict__ Lo) {
  __shared__ float tile[64][68];
  const int b = blockIdx.z;
  const int c0 = blockIdx.y * 64;
  const int t0 = blockIdx.x * 64;
  const int tid = threadIdx.x;
  {
    const int cl = tid >> 2, tg = tid & 3;
    const float* src = X + ((size_t)b * C_ + c0 + cl) * T_ + t0 + tg * 16;
    float4 v0 = *(const float4*)(src);
    float4 v1 = *(const float4*)(src + 4);
    float4 v2 = *(const float4*)(src + 8);
    float4 v3 = *(const float4*)(src + 12);
    float* d = &tile[cl][tg * 16];
    *(float4*)(d) = v0; *(float4*)(d + 4) = v1;
    *(float4*)(d + 8) = v2; *(float4*)(d + 12) = v3;
  }
  __syncthreads();
  {
    const int tl = tid >> 2, cg = tid & 3;
    u16x8 h0, h1, l0, l1;
#pragma unroll
    for (int j = 0; j < 16; ++j) {
      const float v = tile[cg * 16 + j][tl];
      const unsigned short hb = bf16_rne(v);
      const float hf = __builtin_bit_cast(float, (unsigned int)hb << 16);
      const unsigned short lb = bf16_rne(v - hf);
      if (j < 8) { h0[j] = hb; l0[j] = lb; }
      else       { h1[j - 8] = hb; l1[j - 8] = lb; }
    }
    const size_t off = ((size_t)b * T_ + t0 + tl) * C_ + c0 + cg * 16;
    *(u16x8*)(Hi + off) = h0; *(u16x8*)(Hi + off + 8) = h1;
    *(u16x8*)(Lo + off) = l0; *(u16x8*)(Lo + off + 8) = l1;
  }
}

// ------------------------------- MFMA conv ----------------------------------
// Block: 128 co x 256 t, 256 threads (4 waves), wave = 128 co x 64 t
// (8 m-tiles x 4 n-tiles of 16x16). K-chunks of 32 ci; taps via t-shifts.
template <int DIL, bool SNAKE>
__global__ __launch_bounds__(256, 2)
void conv_mfma(const unsigned short* __restrict__ Xhi,  // [b][T][C] bf16 bits
               const unsigned short* __restrict__ Xlo,
               const unsigned short* __restrict__ Wq,   // frag-swizzled (per stage)
               const float* __restrict__ svec,          // this tensor's scale
               const float* __restrict__ bias, const float* __restrict__ aexp,
               const float* __restrict__ invb,
               const float* __restrict__ res,           // fp32 [b][co][t]
               float* __restrict__ Y) {                 // fp32 [b][co][t]
  constexpr int R = 256 + 2 * DIL;  // t-rows incl. halo
  constexpr int RW = 40;            // padded row stride (80 B): 2-way banks, free
  __shared__ unsigned short Xs[2][R * RW];

  const int b = blockIdx.z;
  const int co0 = blockIdx.y * 128;
  const int cob = blockIdx.y * 8;  // co0/16
  const int t0 = blockIdx.x * 256;
  const int tid = threadIdx.x;
  const int lane = tid & 63;
  const int wv = tid >> 6;
  const int l15 = lane & 15;
  const int quad = lane >> 4;

  f32x4 acc[8][4] = {};

  const size_t xbase = (size_t)b * T_ * C_;

#pragma unroll 1
  for (int cc = 0; cc < C_ / 32; ++cc) {
    // ---- stage X tile (hi+lo planes), zero-padded halo ----
    constexpr int XU = R * 8;  // 16 B units
#pragma unroll
    for (int it = 0; it < (XU + 255) / 256; ++it) {
      const int u = it * 256 + tid;
      if (u < XU) {
        const int r = u >> 3, sub = u & 7;
        const int pl = sub >> 2, g = sub & 3;
        const int t = t0 - DIL + r;
        u16x8 v = {0, 0, 0, 0, 0, 0, 0, 0};
        if ((unsigned)t < (unsigned)T_)
          v = *(const u16x8*)((pl ? Xlo : Xhi) + xbase + (size_t)t * C_ + cc * 32 + g * 8);
        *(u16x8*)&Xs[pl][r * RW + g * 8] = v;
      }
    }
    __syncthreads();

#pragma unroll 1
    for (int tap = 0; tap < K_; ++tap) {
      // A-frags: direct global->reg, contiguous 16 B/lane, L2-resident
      const unsigned short* wb =
          Wq + ((((size_t)cc * K_ + tap) * 32 + cob) * 512) + (size_t)lane * 8;
      bf16x8 a[8];
#pragma unroll
      for (int m = 0; m < 8; ++m)
        a[m] = __builtin_bit_cast(bf16x8, *(const u16x8*)(wb + m * 512));
#pragma unroll
      for (int n = 0; n < 4; ++n) {
        const int r = wv * 64 + n * 16 + l15 + tap * DIL;
        const bf16x8 bh = __builtin_bit_cast(bf16x8, *(const u16x8*)&Xs[0][r * RW + quad * 8]);
        const bf16x8 bl = __builtin_bit_cast(bf16x8, *(const u16x8*)&Xs[1][r * RW + quad * 8]);
#pragma unroll
        for (int m = 0; m < 8; ++m) {
          acc[m][n] = __builtin_amdgcn_mfma_f32_16x16x32_bf16(a[m], bh, acc[m][n], 0, 0, 0);
          acc[m][n] = __builtin_amdgcn_mfma_f32_16x16x32_bf16(a[m], bl, acc[m][n], 0, 0, 0);
        }
      }
    }
    __syncthreads();
  }

  // ---- epilogue: scale + bias + (snake | residual) ----
  const float sw = *svec;
#pragma unroll
  for (int m = 0; m < 8; ++m) {
#pragma unroll
    for (int reg = 0; reg < 4; ++reg) {
      const int co = co0 + m * 16 + quad * 4 + reg;
      const float bs = bias[co];
      float av = 0.f, ibv = 0.f;
      if (SNAKE) { av = aexp[co]; ibv = invb[co]; }
#pragma unroll
      for (int n = 0; n < 4; ++n) {
        const int t = t0 + wv * 64 + n * 16 + l15;
        const size_t off = ((size_t)b * C_ + co) * T_ + t;
        float v = sw * acc[m][n][reg] + bs;
        if (SNAKE) {
          const float sn = __sinf(av * v);
          v = v + ibv * sn * sn;
        } else {
          v = v + res[off];
        }
        Y[off] = v;
      }
    }
  }
}

// ------------------------------- launch -------------------------------------
extern "C" void kernel_launch(void* const* d_in, const int* in_sizes, int n_in,
                              void* d_out, int out_size, void* d_ws, size_t ws_size,
                              hipStream_t stream) {
  (void)in_sizes; (void)n_in; (void)out_size; (void)ws_size;
  const float* x = (const float*)d_in[0];
  const float* w1 = (const float*)d_in[1];
  const float* b1 = (const float*)d_in[2];
  const float* al = (const float*)d_in[3];
  const float* be = (const float*)d_in[4];
  const float* w2 = (const float*)d_in[5];
  const float* b2 = (const float*)d_in[6];
  float* out = (float*)d_out;
  char* wsb = (char*)d_ws;

  float* part = (float*)(wsb + OFF_PART);
  float* svec = (float*)(wsb + OFF_S);
  float* ae = (float*)(wsb + OFF_AE);
  float* ib = (float*)(wsb + OFF_IB);
  unsigned short* wq1 = (unsigned short*)(wsb + OFF_WQ1);
  unsigned short* wq2 = (unsigned short*)(wsb + OFF_WQ2);
  float* h = (float*)(wsb + OFF_H);
  unsigned short* Ahi = (unsigned short*)(wsb + OFF_AHI);
  unsigned short* Alo = (unsigned short*)(wsb + OFF_ALO);
  unsigned short* Bhi = (unsigned short*)(wsb + OFF_BHI);
  unsigned short* Blo = (unsigned short*)(wsb + OFF_BLO);

  absmean_partial<<<dim3(96, 6), 256, 0, stream>>>(w1, w2, part);
  absmean_final<<<6, 128, 0, stream>>>(part, svec);
  quantize_kernel<<<(3 * WELEM) / 256, 256, 0, stream>>>(w1, wq1, svec, 0);
  quantize_kernel<<<(3 * WELEM) / 256, 256, 0, stream>>>(w2, wq2, svec, 3);
  snake_params_kernel<<<6, 256, 0, stream>>>(al, be, ae, ib);

  const dim3 tgrid(T_ / 64, C_ / 64, B_);
  const dim3 cgrid(T_ / 256, C_ / 128, B_);

  transpose_split<<<tgrid, 256, 0, stream>>>(x, Ahi, Alo);

  // stage 0 (dil=1)
  conv_mfma<1, true><<<cgrid, 256, 0, stream>>>(Ahi, Alo, wq1 + 0 * (size_t)WELEM, svec + 0,
                                                b1 + 0, ae + 0, ib + 0, nullptr, h);
  transpose_split<<<tgrid, 256, 0, stream>>>(h, Bhi, Blo);
  conv_mfma<1, false><<<cgrid, 256, 0, stream>>>(Bhi, Blo, wq2 + 0 * (size_t)WELEM, svec + 3,
                                                 b2 + 0, nullptr, nullptr, x, out);
  transpose_split<<<tgrid, 256, 0, stream>>>(out, Ahi, Alo);

  // stage 1 (dil=3)
  conv_mfma<3, true><<<cgrid, 256, 0, stream>>>(Ahi, Alo, wq1 + 1 * (size_t)WELEM, svec + 1,
                                                b1 + C_, ae + C_, ib + C_, nullptr, h);
  transpose_split<<<tgrid, 256, 0, stream>>>(h, Bhi, Blo);
  conv_mfma<1, false><<<cgrid, 256, 0, stream>>>(Bhi, Blo, wq2 + 1 * (size_t)WELEM, svec + 4,
                                                 b2 + C_, nullptr, nullptr, out, out);
  transpose_split<<<tgrid, 256, 0, stream>>>(out, Ahi, Alo);

  // stage 2 (dil=5)
  conv_mfma<5, true><<<cgrid, 256, 0, stream>>>(Ahi, Alo, wq1 + 2 * (size_t)WELEM, svec + 2,
                                                b1 + 2 * C_, ae + 2 * C_, ib + 2 * C_, nullptr, h);
  transpose_split<<<tgrid, 256, 0, stream>>>(h, Bhi, Blo);
  conv_mfma<1, false><<<cgrid, 256, 0, stream>>>(Bhi, Blo, wq2 + 2 * (size_t)WELEM, svec + 5,
                                                 b2 + 2 * C_, nullptr, nullptr, out, out);
}

// Round 3
// 860.276 us; speedup vs baseline: 6.9846x; 1.0118x over previous
//
#include <hip/hip_runtime.h>
#include <math.h>
#include <stdint.h>

// ---------------------------------------------------------------------------
// BitResidualBlock via bf16-split MFMA, transposes fused into conv epilogues.
// Ternary weights (exact in bf16) x activations split hi/lo bf16:
//   x = hi + lo  (each product with q in {-1,0,1} is exact; fp32 accum)
// Conv as GEMM: D[co,t] = sum_ci,tap Wq_tap[co,ci] * X[ci, t+(tap-1)*d],
// mfma_f32_16x16x32_bf16, A=W (pre-swizzled, direct global->reg, L2-resident),
// B=X^T [b][t][c] hi/lo staged in LDS (rows padded to 80 B -> 2-way, free).
// conv1 writes ONLY next hi/lo planes (snake fused); conv2 writes fp32 out
// (+bias+residual fused) and, except last stage, the next stage's planes.
// ---------------------------------------------------------------------------

constexpr int B_ = 8, C_ = 512, T_ = 4096, K_ = 3;
constexpr int WELEM = C_ * C_ * K_;  // 786432 per tensor

typedef __bf16 bf16x8 __attribute__((ext_vector_type(8)));
typedef float f32x4 __attribute__((ext_vector_type(4)));
typedef unsigned short u16x8 __attribute__((ext_vector_type(8)));
typedef unsigned short u16x4 __attribute__((ext_vector_type(4)));

// ws byte offsets
constexpr size_t OFF_PART = 0;
constexpr size_t OFF_S = 4096;
constexpr size_t OFF_AE = 8192;
constexpr size_t OFF_IB = 16384;
constexpr size_t OFF_WQ1 = 32768;  // ushort[3*WELEM], frag-swizzled
constexpr size_t OFF_WQ2 = OFF_WQ1 + (size_t)3 * WELEM * 2;
constexpr size_t NBCT = (size_t)B_ * C_ * T_;
constexpr size_t OFF_PHI = OFF_WQ2 + (size_t)3 * WELEM * 2;  // bf16 planes
constexpr size_t OFF_PLO = OFF_PHI + NBCT * 2;
constexpr size_t OFF_QHI = OFF_PLO + NBCT * 2;
constexpr size_t OFF_QLO = OFF_QHI + NBCT * 2;

__device__ inline unsigned short bf16_rne(float v) {
  unsigned int u = __builtin_bit_cast(unsigned int, v);
  unsigned int r = u + 0x7FFFu + ((u >> 16) & 1u);
  return (unsigned short)(r >> 16);
}

// --------------------------- absmean (deterministic) ------------------------
__global__ __launch_bounds__(256)
void absmean_partial(const float* __restrict__ w1, const float* __restrict__ w2,
                     float* __restrict__ part) {
  __shared__ float red[256];
  const int t = blockIdx.y;
  const float* src = (t < 3) ? (w1 + (size_t)t * WELEM) : (w2 + (size_t)(t - 3) * WELEM);
  const int base = blockIdx.x * (256 * 32);
  float v = 0.f;
#pragma unroll
  for (int j = 0; j < 32; ++j) v += fabsf(src[base + j * 256 + threadIdx.x]);
  red[threadIdx.x] = v;
  __syncthreads();
  for (int s = 128; s > 0; s >>= 1) {
    if (threadIdx.x < (unsigned)s) red[threadIdx.x] += red[threadIdx.x + s];
    __syncthreads();
  }
  if (threadIdx.x == 0) part[t * 96 + blockIdx.x] = red[0];
}

__global__ __launch_bounds__(128)
void absmean_final(const float* __restrict__ part, float* __restrict__ svec) {
  __shared__ float red[128];
  const int t = blockIdx.x;
  red[threadIdx.x] = (threadIdx.x < 96) ? part[t * 96 + threadIdx.x] : 0.f;
  __syncthreads();
  for (int s = 64; s > 0; s >>= 1) {
    if (threadIdx.x < (unsigned)s) red[threadIdx.x] += red[threadIdx.x + s];
    __syncthreads();
  }
  if (threadIdx.x == 0) svec[t] = red[0] / (float)WELEM;
}

// --------------------------- quantize -> ternary bf16, frag-swizzled --------
// dst layout: idx = (((st*16 + cc)*3 + tap)*32 + cot)*512 + lane*8 + j
//   where co = cot*16 + (lane&15), ci = cc*32 + (lane>>4)*8 + j.
__global__ __launch_bounds__(256)
void quantize_kernel(const float* __restrict__ src, unsigned short* __restrict__ dst,
                     const float* __restrict__ svec, int sbase) {
  const int idx = blockIdx.x * 256 + threadIdx.x;  // exact grid over 3*WELEM
  const int j = idx & 7;
  const int lane = (idx >> 3) & 63;
  const int cot = (idx >> 9) & 31;
  const int rest = idx >> 14;
  const int tap = rest % 3;
  const int rest2 = rest / 3;
  const int cc = rest2 & 15;
  const int st = rest2 >> 4;
  const int co = cot * 16 + (lane & 15);
  const int ci = cc * 32 + (lane >> 4) * 8 + j;
  const float s = svec[sbase + st];
  const float w = src[(((size_t)st * C_ + co) * C_ + ci) * K_ + tap];
  float q = rintf(w / (s + 1e-5f));
  q = fminf(1.f, fmaxf(-1.f, q));
  dst[idx] = (unsigned short)(__builtin_bit_cast(unsigned int, q) >> 16);
}

__global__ __launch_bounds__(256)
void snake_params_kernel(const float* __restrict__ al, const float* __restrict__ be,
                         float* __restrict__ ae, float* __restrict__ ib) {
  const int idx = blockIdx.x * 256 + threadIdx.x;
  if (idx < 3 * C_) {
    ae[idx] = expf(al[idx]);
    ib[idx] = 1.f / (expf(be[idx]) + 1e-9f);
  }
}

// --------------------------- transpose + hi/lo split (used once, for x) -----
__global__ __launch_bounds__(256)
void transpose_split(const float* __restrict__ X, unsigned short* __restrict__ Hi,
                     unsigned short* __restrict__ Lo) {
  __shared__ float tile[64][68];
  const int b = blockIdx.z;
  const int c0 = blockIdx.y * 64;
  const int t0 = blockIdx.x * 64;
  const int tid = threadIdx.x;
  {
    const int cl = tid >> 2, tg = tid & 3;
    const float* src = X + ((size_t)b * C_ + c0 + cl) * T_ + t0 + tg * 16;
    float4 v0 = *(const float4*)(src);
    float4 v1 = *(const float4*)(src + 4);
    float4 v2 = *(const float4*)(src + 8);
    float4 v3 = *(const float4*)(src + 12);
    float* d = &tile[cl][tg * 16];
    *(float4*)(d) = v0; *(float4*)(d + 4) = v1;
    *(float4*)(d + 8) = v2; *(float4*)(d + 12) = v3;
  }
  __syncthreads();
  {
    const int tl = tid >> 2, cg = tid & 3;
    u16x8 h0, h1, l0, l1;
#pragma unroll
    for (int j = 0; j < 16; ++j) {
      const float v = tile[cg * 16 + j][tl];
      const unsigned short hb = bf16_rne(v);
      const float hf = __builtin_bit_cast(float, (unsigned int)hb << 16);
      const unsigned short lb = bf16_rne(v - hf);
      if (j < 8) { h0[j] = hb; l0[j] = lb; }
      else       { h1[j - 8] = hb; l1[j - 8] = lb; }
    }
    const size_t off = ((size_t)b * T_ + t0 + tl) * C_ + c0 + cg * 16;
    *(u16x8*)(Hi + off) = h0; *(u16x8*)(Hi + off + 8) = h1;
    *(u16x8*)(Lo + off) = l0; *(u16x8*)(Lo + off + 8) = l1;
  }
}

// ------------------------------- MFMA conv ----------------------------------
// Block: 128 co x 256 t, 256 threads (4 waves), wave = 128 co x 64 t
// (8 m-tiles x 4 n-tiles of 16x16). K-chunks of 32 ci; taps via t-shifts.
// Epilogue fuses: scale+bias, then SNAKE or (+res, fp32 store), and optional
// direct transposed hi/lo bf16 plane stores for the next conv's input.
template <int DIL, bool SNAKE, bool PLANES, bool WF32>
__global__ __launch_bounds__(256, 2)
void conv_mfma(const unsigned short* __restrict__ Xhi,  // [b][T][C] bf16 bits
               const unsigned short* __restrict__ Xlo,
               const unsigned short* __restrict__ Wq,   // frag-swizzled
               const float* __restrict__ svec,
               const float* __restrict__ bias, const float* __restrict__ aexp,
               const float* __restrict__ invb,
               const float* __restrict__ res,           // fp32 [b][co][t]
               float* __restrict__ Y,                   // fp32 [b][co][t]
               unsigned short* __restrict__ Ohi,        // [b][T][C] planes
               unsigned short* __restrict__ Olo) {
  constexpr int R = 256 + 2 * DIL;
  constexpr int RW = 40;  // padded row stride (80 B): 2-way banks, free
  __shared__ unsigned short Xs[2][R * RW];

  const int b = blockIdx.z;
  const int co0 = blockIdx.y * 128;
  const int cob = blockIdx.y * 8;
  const int t0 = blockIdx.x * 256;
  const int tid = threadIdx.x;
  const int lane = tid & 63;
  const int wv = tid >> 6;
  const int l15 = lane & 15;
  const int quad = lane >> 4;

  f32x4 acc[8][4] = {};

  const size_t xbase = (size_t)b * T_ * C_;

#pragma unroll 1
  for (int cc = 0; cc < C_ / 32; ++cc) {
    constexpr int XU = R * 8;  // 16 B units
#pragma unroll
    for (int it = 0; it < (XU + 255) / 256; ++it) {
      const int u = it * 256 + tid;
      if (u < XU) {
        const int r = u >> 3, sub = u & 7;
        const int pl = sub >> 2, g = sub & 3;
        const int t = t0 - DIL + r;
        u16x8 v = {0, 0, 0, 0, 0, 0, 0, 0};
        if ((unsigned)t < (unsigned)T_)
          v = *(const u16x8*)((pl ? Xlo : Xhi) + xbase + (size_t)t * C_ + cc * 32 + g * 8);
        *(u16x8*)&Xs[pl][r * RW + g * 8] = v;
      }
    }
    __syncthreads();

#pragma unroll 1
    for (int tap = 0; tap < K_; ++tap) {
      const unsigned short* wb =
          Wq + ((((size_t)cc * K_ + tap) * 32 + cob) * 512) + (size_t)lane * 8;
      bf16x8 a[8];
#pragma unroll
      for (int m = 0; m < 8; ++m)
        a[m] = __builtin_bit_cast(bf16x8, *(const u16x8*)(wb + m * 512));
#pragma unroll
      for (int n = 0; n < 4; ++n) {
        const int r = wv * 64 + n * 16 + l15 + tap * DIL;
        const bf16x8 bh = __builtin_bit_cast(bf16x8, *(const u16x8*)&Xs[0][r * RW + quad * 8]);
        const bf16x8 bl = __builtin_bit_cast(bf16x8, *(const u16x8*)&Xs[1][r * RW + quad * 8]);
#pragma unroll
        for (int m = 0; m < 8; ++m) {
          acc[m][n] = __builtin_amdgcn_mfma_f32_16x16x32_bf16(a[m], bh, acc[m][n], 0, 0, 0);
          acc[m][n] = __builtin_amdgcn_mfma_f32_16x16x32_bf16(a[m], bl, acc[m][n], 0, 0, 0);
        }
      }
    }
    __syncthreads();
  }

  // ---- fused epilogue ----
  const float sw = *svec;
#pragma unroll
  for (int m = 0; m < 8; ++m) {
    const int cb = co0 + m * 16 + quad * 4;  // 4 consecutive co via reg
    float bs[4], av[4], ibv[4];
#pragma unroll
    for (int reg = 0; reg < 4; ++reg) {
      bs[reg] = bias[cb + reg];
      if (SNAKE) { av[reg] = aexp[cb + reg]; ibv[reg] = invb[cb + reg]; }
    }
#pragma unroll
    for (int n = 0; n < 4; ++n) {
      const int t = t0 + wv * 64 + n * 16 + l15;
      float vv[4];
#pragma unroll
      for (int reg = 0; reg < 4; ++reg) {
        float v = sw * acc[m][n][reg] + bs[reg];
        if (SNAKE) {
          const float sn = __sinf(av[reg] * v);
          v = v + ibv[reg] * sn * sn;
        } else {
          v = v + res[((size_t)b * C_ + cb + reg) * T_ + t];
        }
        if (WF32) Y[((size_t)b * C_ + cb + reg) * T_ + t] = v;
        vv[reg] = v;
      }
      if (PLANES) {
        u16x4 hq, lq;
#pragma unroll
        for (int reg = 0; reg < 4; ++reg) {
          const unsigned short hb = bf16_rne(vv[reg]);
          const float hf = __builtin_bit_cast(float, (unsigned int)hb << 16);
          hq[reg] = hb;
          lq[reg] = bf16_rne(vv[reg] - hf);
        }
        const size_t poff = ((size_t)b * T_ + t) * C_ + cb;
        *(u16x4*)(Ohi + poff) = hq;
        *(u16x4*)(Olo + poff) = lq;
      }
    }
  }
}

// ------------------------------- launch -------------------------------------
extern "C" void kernel_launch(void* const* d_in, const int* in_sizes, int n_in,
                              void* d_out, int out_size, void* d_ws, size_t ws_size,
                              hipStream_t stream) {
  (void)in_sizes; (void)n_in; (void)out_size; (void)ws_size;
  const float* x = (const float*)d_in[0];
  const float* w1 = (const float*)d_in[1];
  const float* b1 = (const float*)d_in[2];
  const float* al = (const float*)d_in[3];
  const float* be = (const float*)d_in[4];
  const float* w2 = (const float*)d_in[5];
  const float* b2 = (const float*)d_in[6];
  float* out = (float*)d_out;
  char* wsb = (char*)d_ws;

  float* part = (float*)(wsb + OFF_PART);
  float* svec = (float*)(wsb + OFF_S);
  float* ae = (float*)(wsb + OFF_AE);
  float* ib = (float*)(wsb + OFF_IB);
  unsigned short* wq1 = (unsigned short*)(wsb + OFF_WQ1);
  unsigned short* wq2 = (unsigned short*)(wsb + OFF_WQ2);
  unsigned short* Phi = (unsigned short*)(wsb + OFF_PHI);
  unsigned short* Plo = (unsigned short*)(wsb + OFF_PLO);
  unsigned short* Qhi = (unsigned short*)(wsb + OFF_QHI);
  unsigned short* Qlo = (unsigned short*)(wsb + OFF_QLO);

  absmean_partial<<<dim3(96, 6), 256, 0, stream>>>(w1, w2, part);
  absmean_final<<<6, 128, 0, stream>>>(part, svec);
  quantize_kernel<<<(3 * WELEM) / 256, 256, 0, stream>>>(w1, wq1, svec, 0);
  quantize_kernel<<<(3 * WELEM) / 256, 256, 0, stream>>>(w2, wq2, svec, 3);
  snake_params_kernel<<<6, 256, 0, stream>>>(al, be, ae, ib);

  const dim3 tgrid(T_ / 64, C_ / 64, B_);
  const dim3 cgrid(T_ / 256, C_ / 128, B_);

  transpose_split<<<tgrid, 256, 0, stream>>>(x, Phi, Plo);

  // stage 0 (dil=1): conv1 P->Q planes; conv2 Q->out fp32 + P planes
  conv_mfma<1, true, true, false><<<cgrid, 256, 0, stream>>>(
      Phi, Plo, wq1 + 0 * (size_t)WELEM, svec + 0, b1 + 0, ae + 0, ib + 0,
      nullptr, nullptr, Qhi, Qlo);
  conv_mfma<1, false, true, true><<<cgrid, 256, 0, stream>>>(
      Qhi, Qlo, wq2 + 0 * (size_t)WELEM, svec + 3, b2 + 0, nullptr, nullptr,
      x, out, Phi, Plo);

  // stage 1 (dil=3)
  conv_mfma<3, true, true, false><<<cgrid, 256, 0, stream>>>(
      Phi, Plo, wq1 + 1 * (size_t)WELEM, svec + 1, b1 + C_, ae + C_, ib + C_,
      nullptr, nullptr, Qhi, Qlo);
  conv_mfma<1, false, true, true><<<cgrid, 256, 0, stream>>>(
      Qhi, Qlo, wq2 + 1 * (size_t)WELEM, svec + 4, b2 + C_, nullptr, nullptr,
      out, out, Phi, Plo);

  // stage 2 (dil=5): final conv2 writes fp32 only
  conv_mfma<5, true, true, false><<<cgrid, 256, 0, stream>>>(
      Phi, Plo, wq1 + 2 * (size_t)WELEM, svec + 2, b1 + 2 * C_, ae + 2 * C_,
      ib + 2 * C_, nullptr, nullptr, Qhi, Qlo);
  conv_mfma<1, false, false, true><<<cgrid, 256, 0, stream>>>(
      Qhi, Qlo, wq2 + 2 * (size_t)WELEM, svec + 5, b2 + 2 * C_, nullptr, nullptr,
      out, out, nullptr, nullptr);
}